// Round 3
// baseline (1272.031 us; speedup 1.0000x reference)
//
#include <hip/hip_runtime.h>
#include <math.h>

#define NN 50000
#define NE 800000
#define TDIM 100
#define EDIM 101

typedef _Float16 half4 __attribute__((ext_vector_type(4)));
typedef _Float16 half8 __attribute__((ext_vector_type(8)));
typedef float f32x4 __attribute__((ext_vector_type(4)));

union U16 { uint4 u; half8 h; };

// cos(x) matching np.cos(float32) to ~1e-6: 2-term Cody-Waite into
// revolutions + hardware v_cos_f32 (native revolutions input).
__device__ __forceinline__ float ref_cosf(float x) {
  const float C1 = 0.15915494f;
  const float C2 = 6.42063831e-9f;
  float p = x * C1;
  float r = __fmaf_rn(x, C1, -p);
  r = __fmaf_rn(x, C2, r);
  float n = rintf(p);
  float f = (p - n) + r;
  return __builtin_amdgcn_cosf(f);
}

// ---------------- projection GEMM: [NN,128] x [128,512] -> Q|K16|V16|S -----
#define PBK 16
__global__ void k_proj(
    const float* __restrict__ x,
    const float* __restrict__ Wq, const float* __restrict__ bq,
    const float* __restrict__ Wk, const float* __restrict__ bk,
    const float* __restrict__ Wv, const float* __restrict__ bv,
    const float* __restrict__ Wskip, const float* __restrict__ bskip,
    float* __restrict__ Q, _Float16* __restrict__ K16,
    _Float16* __restrict__ V16, float* __restrict__ S2)
{
  __shared__ float a_s[PBK][68];
  __shared__ float b_s[PBK][64];

  const int tid = threadIdx.x;
  const int cy = blockIdx.x;              // 0..7: 64-col slice of 512
  const int n0 = blockIdx.y * 64;

  const float* W    = (cy < 2) ? Wq : (cy < 4) ? Wk : (cy < 6) ? Wv : Wskip;
  const float* bias = (cy < 2) ? bq : (cy < 4) ? bk : (cy < 6) ? bv : bskip;
  const int cb = (cy & 1) * 64;

  const int ty = tid >> 4, tx = tid & 15;
  const int lrow = tid >> 2, lk4 = (tid & 3) << 2;
  const int lc = tid & 63, lk0 = tid >> 6;

  float acc[4][4];
#pragma unroll
  for (int r = 0; r < 4; ++r)
#pragma unroll
    for (int j = 0; j < 4; ++j) acc[r][j] = 0.f;

  for (int kt = 0; kt < 128; kt += PBK) {
    float4 av = make_float4(0.f, 0.f, 0.f, 0.f);
    if (n0 + lrow < NN)
      av = *(const float4*)&x[(size_t)(n0 + lrow) * 128 + kt + lk4];
    a_s[lk4 + 0][lrow] = av.x; a_s[lk4 + 1][lrow] = av.y;
    a_s[lk4 + 2][lrow] = av.z; a_s[lk4 + 3][lrow] = av.w;
#pragma unroll
    for (int i = 0; i < 4; ++i) {
      int k = lk0 + (i << 2);
      b_s[k][lc] = W[(kt + k) * 128 + cb + lc];
    }
    __syncthreads();
#pragma unroll
    for (int k = 0; k < PBK; ++k) {
      float4 a = *(const float4*)&a_s[k][ty << 2];
      float4 b = *(const float4*)&b_s[k][tx << 2];
      acc[0][0] = fmaf(a.x, b.x, acc[0][0]); acc[0][1] = fmaf(a.x, b.y, acc[0][1]);
      acc[0][2] = fmaf(a.x, b.z, acc[0][2]); acc[0][3] = fmaf(a.x, b.w, acc[0][3]);
      acc[1][0] = fmaf(a.y, b.x, acc[1][0]); acc[1][1] = fmaf(a.y, b.y, acc[1][1]);
      acc[1][2] = fmaf(a.y, b.z, acc[1][2]); acc[1][3] = fmaf(a.y, b.w, acc[1][3]);
      acc[2][0] = fmaf(a.z, b.x, acc[2][0]); acc[2][1] = fmaf(a.z, b.y, acc[2][1]);
      acc[2][2] = fmaf(a.z, b.z, acc[2][2]); acc[2][3] = fmaf(a.z, b.w, acc[2][3]);
      acc[3][0] = fmaf(a.w, b.x, acc[3][0]); acc[3][1] = fmaf(a.w, b.y, acc[3][1]);
      acc[3][2] = fmaf(a.w, b.z, acc[3][2]); acc[3][3] = fmaf(a.w, b.w, acc[3][3]);
    }
    __syncthreads();
  }

  float4 bb = *(const float4*)&bias[cb + (tx << 2)];
  if (cy < 2 || cy >= 6) {
    float* dst = (cy < 2) ? Q : S2;
#pragma unroll
    for (int r = 0; r < 4; ++r) {
      int row = n0 + (ty << 2) + r;
      if (row < NN) {
        float4 o = make_float4(acc[r][0] + bb.x, acc[r][1] + bb.y,
                               acc[r][2] + bb.z, acc[r][3] + bb.w);
        *(float4*)&dst[(size_t)row * 128 + cb + (tx << 2)] = o;
      }
    }
  } else {
    _Float16* dst = (cy < 4) ? K16 : V16;
#pragma unroll
    for (int r = 0; r < 4; ++r) {
      int row = n0 + (ty << 2) + r;
      if (row < NN) {
        half4 h;
        h.x = (_Float16)(acc[r][0] + bb.x); h.y = (_Float16)(acc[r][1] + bb.y);
        h.z = (_Float16)(acc[r][2] + bb.z); h.w = (_Float16)(acc[r][3] + bb.w);
        *(half4*)&dst[(size_t)row * 128 + cb + (tx << 2)] = h;
      }
    }
  }
}

// ---------------- We^T A-fragment precompute (32 KB) -----------------------
// frag[(ks*8+mt)*64+lane] = 8 f16: A[m=lane&15 (ch in tile mt)][k=(lane>>4)*8+jj]
//   = We[j = ks*32+(lane>>4)*8+jj][mt*16+(lane&15)], zero for j>100.
__global__ void k_wefrag(const float* __restrict__ We, uint4* __restrict__ frag) {
  int idx = blockIdx.x * 256 + threadIdx.x;
  if (idx >= 2048) return;
  int lane = idx & 63, fi = idx >> 6;
  int ks = fi >> 3, mt = fi & 7;
  int ch = mt * 16 + (lane & 15);
  int k0 = ks * 32 + ((lane >> 4) << 3);
  U16 cv;
#pragma unroll
  for (int jj = 0; jj < 8; ++jj) {
    int j = k0 + jj;
    cv.h[jj] = (j <= 100) ? (_Float16)We[j * 128 + ch] : (_Float16)0.f;
  }
  frag[idx] = cv.u;
}

// ---------------- CSR build ----------------
__global__ void k_deg(const int* __restrict__ ei, int* __restrict__ deg) {
  int e = blockIdx.x * 256 + threadIdx.x;
  if (e < NE) atomicAdd(&deg[ei[NE + e]], 1);
}

#define SCHUNK 49
__global__ __launch_bounds__(1024) void k_scan(const int* __restrict__ deg,
                                               int* __restrict__ off) {
  __shared__ int s[1024];
  const int t = threadIdx.x;
  const int base = t * SCHUNK;
  int sum = 0;
#pragma unroll 7
  for (int i = 0; i < SCHUNK; ++i) {
    int idx = base + i;
    sum += (idx < NN) ? deg[idx] : 0;
  }
  s[t] = sum;
  __syncthreads();
  for (int o = 1; o < 1024; o <<= 1) {
    int v = 0;
    if (t >= o) v = s[t - o];
    __syncthreads();
    if (t >= o) s[t] += v;
    __syncthreads();
  }
  int run = s[t] - sum;   // exclusive
  for (int i = 0; i < SCHUNK; ++i) {
    int idx = base + i;
    if (idx < NN) { off[idx] = run; run += deg[idx]; }
  }
  if (t == 1023) off[NN] = s[1023];
}

__global__ void k_fill(const int* __restrict__ ei, const int* __restrict__ off,
                       int* __restrict__ cur, int* __restrict__ elist) {
  int e = blockIdx.x * 256 + threadIdx.x;
  if (e < NE) {
    int d = ei[NE + e];
    int p = atomicAdd(&cur[d], 1);
    elist[off[d] + p] = e;
  }
}

// ---------------- fused MFMA attention: one wave per dst node ---------------
// Per 16-edge batch: e^T = We^T(A, LDS frags) x attr^T(B, in-reg) via
// 32x mfma_f32_16x16x32_f16. Lane owns edge=lane&15, chs mt*16+(lane>>4)*4+r.
__global__ __launch_bounds__(256, 3) void k_main(
    const float* __restrict__ Q, const _Float16* __restrict__ K16,
    const _Float16* __restrict__ V16, const float* __restrict__ S2,
    const float* __restrict__ Wt, const float* __restrict__ bt,
    const uint4* __restrict__ wefrag,
    const float* __restrict__ gamma, const float* __restrict__ beta,
    const float* __restrict__ msg, const int* __restrict__ last_update,
    const int* __restrict__ ei, const int* __restrict__ tt,
    const int* __restrict__ off, const int* __restrict__ elist,
    float* __restrict__ out)
{
  __shared__ uint4 wef_s[2048];      // 32 KB: We^T A-fragments
  __shared__ float2 wtbt_s[104];     // (Wt[j], bt[j])

  for (int i = threadIdx.x; i < 2048; i += 256) wef_s[i] = wefrag[i];
  if (threadIdx.x < 104) {
    int j = threadIdx.x;
    wtbt_s[j] = make_float2(j < TDIM ? Wt[j] : 0.f, j < TDIM ? bt[j] : 0.f);
  }
  __syncthreads();

  const int wid = threadIdx.x >> 6, lane = threadIdx.x & 63;
  const int node = blockIdx.x * 4 + wid;          // grid exact: 12500*4 = NN
  const int g = lane >> 4, ed = lane & 15;

  const int o0 = off[node];
  const int deg = off[node + 1] - o0;

  float4 q4[8];
#pragma unroll
  for (int mt = 0; mt < 8; ++mt)
    q4[mt] = *(const float4*)&Q[(size_t)node * 128 + mt * 16 + g * 4];

  float mh[4] = {-INFINITY, -INFINITY, -INFINITY, -INFINITY};
  float lh[4] = {0.f, 0.f, 0.f, 0.f};
  float acc[8][4] = {};

  for (int cb = 0; cb < deg; cb += 16) {
    int cnt = deg - cb; if (cnt > 16) cnt = 16;

    float rel = 0.f, mg = 0.f; int srcl = 0;
    if (lane < cnt) {
      int eid = elist[o0 + cb + lane];
      srcl = ei[eid];
      mg = msg[eid];
      rel = (float)(last_update[srcl] - tt[eid]);
    }
    float rel_b = __shfl(rel, ed);
    float mg_b  = __shfl(mg, ed);
    int   src_b = __shfl(srcl, ed);

    // B-fragments (attr^T): lane holds attr[edge=ed][j=ks*32+g*8+jj]
    half8 bf[4];
#pragma unroll
    for (int ks = 0; ks < 3; ++ks)
#pragma unroll
      for (int jj = 0; jj < 8; ++jj) {
        float2 wb = wtbt_s[ks * 32 + g * 8 + jj];
        bf[ks][jj] = (_Float16)ref_cosf(__fmaf_rn(rel_b, wb.x, wb.y));
      }
    {
#pragma unroll
      for (int jj = 0; jj < 8; ++jj) bf[3][jj] = (_Float16)0.f;
      if (g == 0) {
#pragma unroll
        for (int jj = 0; jj < 4; ++jj) {
          float2 wb = wtbt_s[96 + jj];
          bf[3][jj] = (_Float16)ref_cosf(__fmaf_rn(rel_b, wb.x, wb.y));
        }
        bf[3][4] = (_Float16)mg_b;
      }
    }

    // e^T tiles via MFMA; ec[mt][r] = e[ed][mt*16+g*4+r]
    f32x4 ec[8];
#pragma unroll
    for (int mt = 0; mt < 8; ++mt) {
      f32x4 c = {0.f, 0.f, 0.f, 0.f};
#pragma unroll
      for (int ks = 0; ks < 4; ++ks) {
        U16 cv; cv.u = wef_s[(ks * 8 + mt) * 64 + lane];
        c = __builtin_amdgcn_mfma_f32_16x16x32_f16(cv.h, bf[ks], c, 0, 0, 0);
      }
      ec[mt] = c;
    }

    // per-head alpha partials
    float pal[4] = {0.f, 0.f, 0.f, 0.f};
#pragma unroll
    for (int mt = 0; mt < 8; ++mt) {
      half4 kh = *(const half4*)&K16[(size_t)src_b * 128 + mt * 16 + g * 4];
      int h = mt >> 1;
      pal[h] = fmaf(q4[mt].x, (float)kh.x + ec[mt][0], pal[h]);
      pal[h] = fmaf(q4[mt].y, (float)kh.y + ec[mt][1], pal[h]);
      pal[h] = fmaf(q4[mt].z, (float)kh.z + ec[mt][2], pal[h]);
      pal[h] = fmaf(q4[mt].w, (float)kh.w + ec[mt][3], pal[h]);
    }

    bool valid = ed < cnt;
    float sc[4], w[4];
#pragma unroll
    for (int h = 0; h < 4; ++h) {
      float p = pal[h];
      p += __shfl_xor(p, 16); p += __shfl_xor(p, 32);   // sum chs across groups
      p = valid ? p * 0.17677669529663689f : -INFINITY;
      float bm = p;
      bm = fmaxf(bm, __shfl_xor(bm, 1)); bm = fmaxf(bm, __shfl_xor(bm, 2));
      bm = fmaxf(bm, __shfl_xor(bm, 4)); bm = fmaxf(bm, __shfl_xor(bm, 8));
      float nm = fmaxf(mh[h], bm);
      sc[h] = __expf(mh[h] - nm);
      w[h] = __expf(p - nm);
      float ls = w[h];
      ls += __shfl_xor(ls, 1); ls += __shfl_xor(ls, 2);
      ls += __shfl_xor(ls, 4); ls += __shfl_xor(ls, 8);
      lh[h] = lh[h] * sc[h] + ls;
      mh[h] = nm;
    }

#pragma unroll
    for (int mt = 0; mt < 8; ++mt) {
      half4 vh = *(const half4*)&V16[(size_t)src_b * 128 + mt * 16 + g * 4];
      int h = mt >> 1;
      acc[mt][0] = fmaf(w[h], (float)vh.x + ec[mt][0], acc[mt][0] * sc[h]);
      acc[mt][1] = fmaf(w[h], (float)vh.y + ec[mt][1], acc[mt][1] * sc[h]);
      acc[mt][2] = fmaf(w[h], (float)vh.z + ec[mt][2], acc[mt][2] * sc[h]);
      acc[mt][3] = fmaf(w[h], (float)vh.w + ec[mt][3], acc[mt][3] * sc[h]);
    }
  }

  // reduce over the 16 edge-lanes within each group
#pragma unroll
  for (int mt = 0; mt < 8; ++mt)
#pragma unroll
    for (int r = 0; r < 4; ++r) {
      float v = acc[mt][r];
      v += __shfl_xor(v, 1); v += __shfl_xor(v, 2);
      v += __shfl_xor(v, 4); v += __shfl_xor(v, 8);
      acc[mt][r] = v;
    }

  float inv[4];
#pragma unroll
  for (int h = 0; h < 4; ++h) inv[h] = 1.f / (lh[h] + 1e-16f);

  float sum = 0.f;
#pragma unroll
  for (int mt = 0; mt < 8; ++mt) {
    float4 s4 = *(const float4*)&S2[(size_t)node * 128 + mt * 16 + g * 4];
    int h = mt >> 1;
    acc[mt][0] = fmaxf(fmaf(acc[mt][0], inv[h], s4.x), 0.f);
    acc[mt][1] = fmaxf(fmaf(acc[mt][1], inv[h], s4.y), 0.f);
    acc[mt][2] = fmaxf(fmaf(acc[mt][2], inv[h], s4.z), 0.f);
    acc[mt][3] = fmaxf(fmaf(acc[mt][3], inv[h], s4.w), 0.f);
    sum += acc[mt][0] + acc[mt][1] + acc[mt][2] + acc[mt][3];
  }
  sum += __shfl_xor(sum, 16); sum += __shfl_xor(sum, 32);
  float mu = sum * 0.0078125f;
  float vs = 0.f;
#pragma unroll
  for (int mt = 0; mt < 8; ++mt)
#pragma unroll
    for (int r = 0; r < 4; ++r) {
      float d = acc[mt][r] - mu;
      vs = fmaf(d, d, vs);
      acc[mt][r] = d;
    }
  vs += __shfl_xor(vs, 16); vs += __shfl_xor(vs, 32);
  float rstd = rsqrtf(vs * 0.0078125f + 1e-5f);

#pragma unroll
  for (int mt = 0; mt < 8; ++mt) {
    float4 g4 = *(const float4*)&gamma[mt * 16 + g * 4];
    float4 b4 = *(const float4*)&beta[mt * 16 + g * 4];
    float v0 = acc[mt][0] * rstd * g4.x + b4.x;
    float v1 = acc[mt][1] * rstd * g4.y + b4.y;
    float v2 = acc[mt][2] * rstd * g4.z + b4.z;
    float v3 = acc[mt][3] * rstd * g4.w + b4.w;
    if (ed == mt)
      *(float4*)&out[(size_t)node * 128 + mt * 16 + g * 4] =
          make_float4(v0, v1, v2, v3);
  }
}

// ---------------- launch ----------------
// ws layout (bytes):
//   Q 0 | S 25.6e6 | K16 51.2e6 | V16 64.0e6 | deg 76.8e6 | cur 77.0e6
//   off 77.2e6 | elist 77,400,064 | wefrag 80,600,064 | end 80,632,832
extern "C" void kernel_launch(void* const* d_in, const int* in_sizes, int n_in,
                              void* d_out, int out_size, void* d_ws, size_t ws_size,
                              hipStream_t stream)
{
  (void)in_sizes; (void)n_in; (void)out_size;
  if (ws_size < 80632832u) return;

  const float* x     = (const float*)d_in[0];
  const float* msg   = (const float*)d_in[1];
  const float* Wt    = (const float*)d_in[2];
  const float* bt    = (const float*)d_in[3];
  const float* Wq    = (const float*)d_in[4];
  const float* bq    = (const float*)d_in[5];
  const float* Wk    = (const float*)d_in[6];
  const float* bk    = (const float*)d_in[7];
  const float* Wv    = (const float*)d_in[8];
  const float* bv    = (const float*)d_in[9];
  const float* We    = (const float*)d_in[10];
  const float* Wskip = (const float*)d_in[11];
  const float* bskip = (const float*)d_in[12];
  const float* gamma = (const float*)d_in[13];
  const float* beta  = (const float*)d_in[14];
  const int* last_update = (const int*)d_in[15];
  const int* ei    = (const int*)d_in[16];
  const int* tt    = (const int*)d_in[17];

  char* ws = (char*)d_ws;
  float*    Q    = (float*)(ws);
  float*    S2   = (float*)(ws + 25600000);
  _Float16* K16  = (_Float16*)(ws + 51200000);
  _Float16* V16  = (_Float16*)(ws + 64000000);
  int* deg   = (int*)(ws + 76800000);
  int* cur   = (int*)(ws + 77000000);
  int* off   = (int*)(ws + 77200000);
  int* elist = (int*)(ws + 77400064);
  uint4* wef = (uint4*)(ws + 80600064);

  hipMemsetAsync(deg, 0, 400000, stream);              // deg + cur
  k_wefrag<<<8, 256, 0, stream>>>(We, wef);
  k_deg <<<(NE + 255) / 256, 256, 0, stream>>>(ei, deg);
  k_scan<<<1, 1024, 0, stream>>>(deg, off);
  k_fill<<<(NE + 255) / 256, 256, 0, stream>>>(ei, off, cur, elist);
  dim3 pg(8, (NN + 63) / 64);
  k_proj<<<pg, 256, 0, stream>>>(x, Wq, bq, Wk, bk, Wv, bv,
                                 Wskip, bskip, Q, K16, V16, S2);
  k_main<<<NN / 4, 256, 0, stream>>>(Q, K16, V16, S2, Wt, bt, wef, gamma, beta,
                                     msg, last_update, ei, tt, off, elist,
                                     (float*)d_out);
}